// Round 5
// baseline (66.592 us; speedup 1.0000x reference)
//
#include <hip/hip_runtime.h>

// TemporalCorrelation as band-GEMM on MFMA, C-split for occupancy.
// out[b,o,t] = <f1[b,:,t], f2[b,:,clamp(t+o-10)]> / (||f1[:,t]|| ||f2[:,t']||)
// Block: 512 thr (8 waves). Waves 0-3: channels [0,512); waves 4-7: [512,1024).
// Tile: 64 t-cols; wave (h,wm) computes M-tile wm x N-tiles wm..wm+2 of the
// 96-col f2 window over its channel half; halves merged via LDS at the end.
// LDS tiles stored in lane-read order (16B/lane) -> ds_read_b128 conflict-free;
// 1040B tile stride spreads the packed b32 writes to 2-way (free).

constexpr int B    = 8;
constexpr int C    = 1024;
constexpr int T    = 4096;
constexpr int NO   = 21;
constexpr int MD   = 10;
constexpr int CH   = 512;    // channels per half
constexpr int NCHK = 16;     // K-chunks (32 ch) per half
constexpr int TSTR = 520;    // tile stride in hw (1040 B = 65*16)
constexpr int HBUF = 5200;   // half-buffer size in hw (10 tiles)

typedef __attribute__((ext_vector_type(8))) short short8;
typedef __attribute__((ext_vector_type(4))) float f32x4;

__device__ inline unsigned bf16rne(float f) {
    unsigned u = __float_as_uint(f);
    return (u + 0x7FFFu + ((u >> 16) & 1u)) >> 16;   // RNE bf16 in low 16
}
__device__ inline unsigned pack2(float lo, float hi) {
    return bf16rne(lo) | (bf16rne(hi) << 16);
}

struct Regs { float4 a0, a1, b0, b0b, b1, b1b; };

__global__ __launch_bounds__(512)
void corr_mfma(const float* __restrict__ f1, const float* __restrict__ f2,
               float* __restrict__ out)
{
    __shared__ short8 stgv[4][650];          // [h*2+buf][...] 41.6 KB
    __shared__ float  sq1buf[64][33];
    __shared__ float  sq2buf[8][96];
    __shared__ float  inv1L[64];
    __shared__ float  inv2L[96];
    __shared__ float  outT[NO][68];

    const int sb   = (int)blockIdx.x;
    const int flat = (sb & 7) * 64 + (sb >> 3);    // XCD swizzle (512%8==0)
    const int b    = flat >> 6;
    const int t0   = (flat & 63) * 64;

    const int tid  = (int)threadIdx.x;
    const int lane = tid & 63;
    const int w    = tid >> 6;                     // 0..7
    const int wm   = w & 3;                        // M-tile id
    const int h    = w >> 2;                       // channel half
    const int ht   = tid & 255;                    // id within half

    // ---- staging maps (within half, constant across chunks) ----
    const int u1 = ht & 15;                        // f1 t-run (4 cols)
    const int q1 = ht >> 4;                        // f1 c-pair: rows 2q1,2q1+1
    const int r2 = ht & 15;                        // f2 window run
    const int q2 = ht >> 4;                        // f2 c-pair
    const bool x2 = (r2 < 8);                      // also stages run 16+r2

    const float* f1p = f1 + ((size_t)(b * C + h * CH + 2 * q1)) * T + t0 + 4 * u1;
    const float* f2p = f2 + ((size_t)(b * C + h * CH + 2 * q2)) * T;
    const int cA = min(max(t0 - 16 + 4 * r2,        0), T - 4);
    const int cB = min(max(t0 - 16 + 4 * (16 + r2), 0), T - 4);

    // tile layout: elem (t,c) at tile*TSTR + ((c>>3)*16 + t)*8 + (c&7)  [hw]
    const int f1hw  = (u1 >> 2) * TSTR + ((q1 >> 2) * 16 + 4 * (u1 & 3)) * 8 + 2 * (q1 & 3);
    const int f2hwA = 4 * TSTR + (r2 >> 2) * TSTR
                    + ((q2 >> 2) * 16 + 4 * (r2 & 3)) * 8 + 2 * (q2 & 3);
    const int f2hwB = f2hwA + 4 * TSTR;            // run 16+r2: tile +4

    // fragment read: lane l reads 16B at l*16 within its tile
    const int fhwA  = wm * TSTR + lane * 8;
    const int fhwB0 = 4 * TSTR + wm * TSTR + lane * 8;

    float sq1[4]  = {0.f, 0.f, 0.f, 0.f};
    float sq2a[4] = {0.f, 0.f, 0.f, 0.f};
    float sq2b[4] = {0.f, 0.f, 0.f, 0.f};
    f32x4 acc0 = {0.f,0.f,0.f,0.f}, acc1 = {0.f,0.f,0.f,0.f}, acc2 = {0.f,0.f,0.f,0.f};

    auto load_chunk = [&](int k) {
        Regs r; const size_t o = (size_t)k * 32 * T;
        r.a0  = *(const float4*)(f1p + o);
        r.a1  = *(const float4*)(f1p + o + T);
        r.b0  = *(const float4*)(f2p + o + cA);
        r.b0b = *(const float4*)(f2p + o + cA + T);
        if (x2) {
            r.b1  = *(const float4*)(f2p + o + cB);
            r.b1b = *(const float4*)(f2p + o + cB + T);
        }
        return r;
    };
    auto commit = [&](const Regs& r, int buf) {
        unsigned short* S = (unsigned short*)&stgv[h * 2 + buf][0];
        const float* a0 = (const float*)&r.a0;  const float* a1  = (const float*)&r.a1;
        const float* b0 = (const float*)&r.b0;  const float* b0b = (const float*)&r.b0b;
        const float* b1 = (const float*)&r.b1;  const float* b1b = (const float*)&r.b1b;
#pragma unroll
        for (int i = 0; i < 4; ++i) {
            *(unsigned*)&S[f1hw  + 8 * i] = pack2(a0[i], a1[i]);
            *(unsigned*)&S[f2hwA + 8 * i] = pack2(b0[i], b0b[i]);
            sq1[i]  += a0[i] * a0[i] + a1[i] * a1[i];
            sq2a[i] += b0[i] * b0[i] + b0b[i] * b0b[i];
        }
        if (x2) {
#pragma unroll
            for (int i = 0; i < 4; ++i) {
                *(unsigned*)&S[f2hwB + 8 * i] = pack2(b1[i], b1b[i]);
                sq2b[i] += b1[i] * b1[i] + b1b[i] * b1b[i];
            }
        }
    };
    auto compute = [&](int buf) {
        const unsigned short* S = (const unsigned short*)&stgv[h * 2 + buf][0];
        short8 af  = *(const short8*)&S[fhwA];
        short8 bf0 = *(const short8*)&S[fhwB0];
        short8 bf1 = *(const short8*)&S[fhwB0 + TSTR];
        short8 bf2 = *(const short8*)&S[fhwB0 + 2 * TSTR];
        acc0 = __builtin_amdgcn_mfma_f32_16x16x32_bf16(af, bf0, acc0, 0, 0, 0);
        acc1 = __builtin_amdgcn_mfma_f32_16x16x32_bf16(af, bf1, acc1, 0, 0, 0);
        acc2 = __builtin_amdgcn_mfma_f32_16x16x32_bf16(af, bf2, acc2, 0, 0, 0);
    };

    // ---- depth-2 pipelined K-loop, double-buffered LDS per half ----
    Regs RA = load_chunk(0), RB = load_chunk(1);
    for (int k = 0; k < NCHK; k += 2) {
        commit(RA, 0);
        __syncthreads();
        if (k + 2 < NCHK) RA = load_chunk(k + 2);
        compute(0);
        commit(RB, 1);
        __syncthreads();
        if (k + 3 < NCHK) RB = load_chunk(k + 3);
        compute(1);
    }

    // ---- norm partials (distinct LDS regions; read after next barrier) ----
#pragma unroll
    for (int e = 0; e < 4; ++e) sq1buf[4 * u1 + e][q1 + 16 * h] = sq1[e];
#pragma unroll
    for (int i = 0; i < 4; ++i) {
        sq2a[i] += __shfl_xor(sq2a[i], 16, 64);
        sq2a[i] += __shfl_xor(sq2a[i], 32, 64);
        sq2b[i] += __shfl_xor(sq2b[i], 16, 64);
        sq2b[i] += __shfl_xor(sq2b[i], 32, 64);
    }
    if (lane < 16) {
#pragma unroll
        for (int i = 0; i < 4; ++i) sq2buf[w][4 * lane + i] = sq2a[i];
    }
    if (lane < 8) {
#pragma unroll
        for (int i = 0; i < 4; ++i) sq2buf[w][64 + 4 * lane + i] = sq2b[i];
    }
    __syncthreads();   // all stage reads done; stage region reusable

    // ---- half-1 publishes accs; norm finalize runs concurrently ----
    f32x4* mrg = (f32x4*)&stgv[0][0];              // 768 x 16B = 12 KB overlay
    if (h == 1) {
        const int mb = (wm * 64 + lane) * 3;
        mrg[mb + 0] = acc0; mrg[mb + 1] = acc1; mrg[mb + 2] = acc2;
    }
    if (tid < 64) {
        float s = 0.f;
#pragma unroll
        for (int g = 0; g < 32; ++g) s += sq1buf[tid][g];
        inv1L[tid] = 1.f / fmaxf(sqrtf(s), 1e-12f);
    } else if (tid < 160) {
        const int f = tid - 64;
        float s = 0.f;
#pragma unroll
        for (int g = 0; g < 8; ++g) s += sq2buf[g][f];
        inv2L[f] = 1.f / fmaxf(sqrtf(s), 1e-12f);
    }
    __syncthreads();

    // ---- half-0 merges and writes the band -> outT (clamp-redirect) ----
    if (h == 0) {
        const int mb = (wm * 64 + lane) * 3;
        f32x4 m0v = mrg[mb + 0], m1v = mrg[mb + 1], m2v = mrg[mb + 2];
#pragma unroll
        for (int r = 0; r < 4; ++r) { acc0[r] += m0v[r]; acc1[r] += m1v[r]; acc2[r] += m2v[r]; }

        const int m0  = t0 + wm * 16;
        const int cr  = lane & 15;            // N-col within tile
        const int rr4 = (lane >> 4) * 4;      // M-row base
#define EPI(nt, A)                                                          \
        {                                                                   \
            const int tp = t0 - 16 + (wm + (nt)) * 16 + cr;                 \
            _Pragma("unroll")                                               \
            for (int r = 0; r < 4; ++r) {                                   \
                const int t = m0 + rr4 + r;                                 \
                const int d = tp - t;                                       \
                if (tp >= 0 && tp < T && d >= -MD && d <= MD) {             \
                    const float val = (A)[r] * inv1L[t - t0] * inv2L[tp - t0 + 16]; \
                    const int on  = d + MD;                                 \
                    const int olo = (tp == 0)     ? 0      : on;            \
                    const int ohi = (tp == T - 1) ? NO - 1 : on;            \
                    for (int o = olo; o <= ohi; ++o) outT[o][t - t0] = val; \
                }                                                           \
            }                                                               \
        }
        EPI(0, acc0) EPI(1, acc1) EPI(2, acc2)
#undef EPI
    }
    __syncthreads();

    // ---- coalesced store ----
    for (int task = tid; task < NO * 16; task += 512) {
        const int o  = task >> 4;
        const int t4 = (task & 15) * 4;
        const float4 v = *(const float4*)&outT[o][t4];
        *(float4*)(out + ((size_t)b * NO + o) * T + t0 + t4) = v;
    }
}

extern "C" void kernel_launch(void* const* d_in, const int* in_sizes, int n_in,
                              void* d_out, int out_size, void* d_ws, size_t ws_size,
                              hipStream_t stream)
{
    const float* f1 = (const float*)d_in[0];
    const float* f2 = (const float*)d_in[1];
    (void)d_ws; (void)ws_size;
    corr_mfma<<<dim3(512), dim3(512), 0, stream>>>(f1, f2, (float*)d_out);
}

// Round 6
// 49.049 us; speedup vs baseline: 1.3577x; 1.3577x over previous
//
#include <hip/hip_runtime.h>

// TemporalCorrelation as band-GEMM on MFMA — round-3 structure + depth-4
// global->reg prefetch (the only change vs the verified 45.8us kernel).
// out[b,o,t] = <f1[b,:,t], f2[b,:,clamp(t+o-10)]> / (||f1[:,t]|| ||f2[:,t']||)
// Block: 256 thr (4 waves), tile = 64 t-cols x all 1024 channels.
// Wave w: M-tile [t0+16w,16), N-tiles w,w+1,w+2 of the 96-col f2 window.
// LDS tiles [16t][32c] bf16 fragment-major -> single ds_read_b128 fragments;
// fp32->bf16 transpose at store via c-pair packed ds_write_b32.

constexpr int B  = 8;
constexpr int C  = 1024;
constexpr int T  = 4096;
constexpr int NO = 21;
constexpr int MD = 10;

typedef __attribute__((ext_vector_type(8))) short short8;
typedef __attribute__((ext_vector_type(4))) float f32x4;

__device__ inline unsigned bf16rne(float f) {
    unsigned u = __float_as_uint(f);
    return (u + 0x7FFFu + ((u >> 16) & 1u)) >> 16;   // RNE bf16 in low 16
}
__device__ inline unsigned pack2(float lo, float hi) {
    return bf16rne(lo) | (bf16rne(hi) << 16);
}

struct Regs { float4 a0, a1, b0, b0b, b1, b1b; };

__global__ __launch_bounds__(256, 2)
void corr_mfma(const float* __restrict__ f1, const float* __restrict__ f2,
               float* __restrict__ out)
{
    __shared__ short8 stgv[2][640];          // 2 x 5120 hw = 20 KB
    __shared__ float  sq1buf[64][17];
    __shared__ float  sq2buf[4][96];
    __shared__ float  inv1L[64];
    __shared__ float  inv2L[96];
    __shared__ float  outT[NO][68];

    const int sb   = (int)blockIdx.x;
    const int flat = (sb & 7) * 64 + (sb >> 3);    // XCD swizzle (512%8==0)
    const int b    = flat >> 6;
    const int t0   = (flat & 63) * 64;

    const int tid  = (int)threadIdx.x;
    const int lane = tid & 63;
    const int w    = tid >> 6;                     // wave id = M-tile id

    // ---- staging maps (constant across chunks) ----
    const int u1 = tid & 15;                       // f1 t-run (4 cols)
    const int q1 = tid >> 4;                       // f1 c-pair: rows 2q1,2q1+1
    const int r2 = tid & 15;                       // f2 window run (4 cols)
    const int q2 = tid >> 4;                       // f2 c-pair
    const bool x2 = (r2 < 8);                      // also stages run 16+r2

    const float* f1p = f1 + ((size_t)b * C + 2 * q1) * T + t0 + 4 * u1;
    const float* f2p = f2 + ((size_t)b * C + 2 * q2) * T;
    const int cA = min(max(t0 - 16 + 4 * r2,        0), T - 4);  // clamped src
    const int cB = min(max(t0 - 16 + 4 * (16 + r2), 0), T - 4);

    // store hw offsets: tile=[16t][32c], elem(t,c) at t*32 + slot'*8 + (c&7),
    // slot' = ((c>>3) + (t>>2)) & 3. Writes step +32 hw per t (i=0..3).
    const int f1hw = (u1 >> 2) * 512 + 4 * (u1 & 3) * 32
                   + ((((q1 >> 2) + (u1 & 3)) & 3) << 3) + 2 * (q1 & 3);
    const int f2hwA = 2048 + (r2 >> 2) * 512 + 4 * (r2 & 3) * 32
                    + ((((q2 >> 2) + (r2 & 3)) & 3) << 3) + 2 * (q2 & 3);
    const int f2hwB = f2hwA + 2048;               // run 16+r2: tile +4

    // fragment read offset: lane wants t=lane&15, c-slot=lane>>4
    const int ft  = lane & 15;
    const int fhw = ft * 32 + ((((lane >> 4) + (ft >> 2)) & 3) << 3);

    float sq1[4]  = {0.f, 0.f, 0.f, 0.f};
    float sq2a[4] = {0.f, 0.f, 0.f, 0.f};
    float sq2b[4] = {0.f, 0.f, 0.f, 0.f};
    f32x4 acc0 = {0.f,0.f,0.f,0.f}, acc1 = {0.f,0.f,0.f,0.f}, acc2 = {0.f,0.f,0.f,0.f};

    auto load_chunk = [&](int k) {
        Regs r; const size_t o = (size_t)k * 32 * T;
        r.a0  = *(const float4*)(f1p + o);
        r.a1  = *(const float4*)(f1p + o + T);
        r.b0  = *(const float4*)(f2p + o + cA);
        r.b0b = *(const float4*)(f2p + o + cA + T);
        if (x2) {
            r.b1  = *(const float4*)(f2p + o + cB);
            r.b1b = *(const float4*)(f2p + o + cB + T);
        }
        return r;
    };
    auto commit = [&](const Regs& r, int buf) {
        unsigned short* S = (unsigned short*)&stgv[buf][0];
        const float* a0 = (const float*)&r.a0;  const float* a1  = (const float*)&r.a1;
        const float* b0 = (const float*)&r.b0;  const float* b0b = (const float*)&r.b0b;
        const float* b1 = (const float*)&r.b1;  const float* b1b = (const float*)&r.b1b;
#pragma unroll
        for (int i = 0; i < 4; ++i) {
            *(unsigned*)&S[f1hw  + 32 * i] = pack2(a0[i], a1[i]);
            *(unsigned*)&S[f2hwA + 32 * i] = pack2(b0[i], b0b[i]);
            sq1[i]  += a0[i] * a0[i] + a1[i] * a1[i];
            sq2a[i] += b0[i] * b0[i] + b0b[i] * b0b[i];
        }
        if (x2) {
#pragma unroll
            for (int i = 0; i < 4; ++i) {
                *(unsigned*)&S[f2hwB + 32 * i] = pack2(b1[i], b1b[i]);
                sq2b[i] += b1[i] * b1[i] + b1b[i] * b1b[i];
            }
        }
    };
    auto compute = [&](int buf) {
        const unsigned short* S = (const unsigned short*)&stgv[buf][0];
        short8 af  = *(const short8*)&S[w * 512 + fhw];
        short8 bf0 = *(const short8*)&S[2048 + (w + 0) * 512 + fhw];
        short8 bf1 = *(const short8*)&S[2048 + (w + 1) * 512 + fhw];
        short8 bf2 = *(const short8*)&S[2048 + (w + 2) * 512 + fhw];
        acc0 = __builtin_amdgcn_mfma_f32_16x16x32_bf16(af, bf0, acc0, 0, 0, 0);
        acc1 = __builtin_amdgcn_mfma_f32_16x16x32_bf16(af, bf1, acc1, 0, 0, 0);
        acc2 = __builtin_amdgcn_mfma_f32_16x16x32_bf16(af, bf2, acc2, 0, 0, 0);
    };

    // ---- depth-4 pipelined K-loop (4 reg buffers, 2 LDS buffers) ----
    Regs R0 = load_chunk(0), R1 = load_chunk(1),
         R2 = load_chunk(2), R3 = load_chunk(3);
    for (int k = 0; k < 32; k += 4) {
        commit(R0, 0);
        __syncthreads();
        if (k + 4 < 32) R0 = load_chunk(k + 4);
        compute(0);
        commit(R1, 1);
        __syncthreads();
        if (k + 5 < 32) R1 = load_chunk(k + 5);
        compute(1);
        commit(R2, 0);
        __syncthreads();
        if (k + 6 < 32) R2 = load_chunk(k + 6);
        compute(0);
        commit(R3, 1);
        __syncthreads();
        if (k + 7 < 32) R3 = load_chunk(k + 7);
        compute(1);
    }

    // ---- norms ----
#pragma unroll
    for (int e = 0; e < 4; ++e) sq1buf[4 * u1 + e][q1] = sq1[e];
#pragma unroll
    for (int i = 0; i < 4; ++i) {
        sq2a[i] += __shfl_xor(sq2a[i], 16, 64);
        sq2a[i] += __shfl_xor(sq2a[i], 32, 64);
        sq2b[i] += __shfl_xor(sq2b[i], 16, 64);
        sq2b[i] += __shfl_xor(sq2b[i], 32, 64);
    }
    if (lane < 16) {
#pragma unroll
        for (int i = 0; i < 4; ++i) sq2buf[w][4 * lane + i] = sq2a[i];
    }
    if (lane < 8) {
#pragma unroll
        for (int i = 0; i < 4; ++i) sq2buf[w][64 + 4 * lane + i] = sq2b[i];
    }
    __syncthreads();
    if (tid < 64) {
        float s = 0.f;
#pragma unroll
        for (int g = 0; g < 16; ++g) s += sq1buf[tid][g];
        inv1L[tid] = 1.f / fmaxf(sqrtf(s), 1e-12f);
    } else if (tid < 160) {
        const int f = tid - 64;
        float s = sq2buf[0][f] + sq2buf[1][f] + sq2buf[2][f] + sq2buf[3][f];
        inv2L[f] = 1.f / fmaxf(sqrtf(s), 1e-12f);
    }
    __syncthreads();

    // ---- epilogue: band elems -> outT with clamp-redirect, then coalesced ----
    const int m0  = t0 + w * 16;
    const int cr  = lane & 15;            // N-col within tile
    const int rr4 = (lane >> 4) * 4;      // M-row base
#define EPI(nt, A)                                                          \
    {                                                                       \
        const int tp = t0 - 16 + (w + (nt)) * 16 + cr;                      \
        _Pragma("unroll")                                                   \
        for (int r = 0; r < 4; ++r) {                                       \
            const int t = m0 + rr4 + r;                                     \
            const int d = tp - t;                                           \
            if (tp >= 0 && tp < T && d >= -MD && d <= MD) {                 \
                const float val = (A)[r] * inv1L[t - t0] * inv2L[tp - t0 + 16]; \
                const int on  = d + MD;                                     \
                const int olo = (tp == 0)     ? 0      : on;                \
                const int ohi = (tp == T - 1) ? NO - 1 : on;                \
                for (int o = olo; o <= ohi; ++o) outT[o][t - t0] = val;     \
            }                                                               \
        }                                                                   \
    }
    EPI(0, acc0) EPI(1, acc1) EPI(2, acc2)
#undef EPI
    __syncthreads();

    for (int task = tid; task < NO * 16; task += 256) {
        const int o  = task >> 4;
        const int t4 = (task & 15) * 4;
        const float4 v = *(const float4*)&outT[o][t4];
        *(float4*)(out + ((size_t)b * NO + o) * T + t0 + t4) = v;
    }
}

extern "C" void kernel_launch(void* const* d_in, const int* in_sizes, int n_in,
                              void* d_out, int out_size, void* d_ws, size_t ws_size,
                              hipStream_t stream)
{
    const float* f1 = (const float*)d_in[0];
    const float* f2 = (const float*)d_in[1];
    (void)d_ws; (void)ws_size;
    corr_mfma<<<dim3(512), dim3(256), 0, stream>>>(f1, f2, (float*)d_out);
}